// Round 14
// baseline (139.253 us; speedup 1.0000x reference)
//
#include <hip/hip_runtime.h>
#include <hip/hip_bf16.h>

typedef unsigned short u16;
typedef unsigned int u32;
typedef __attribute__((ext_vector_type(8))) short short8;
typedef __attribute__((ext_vector_type(8))) __bf16 bf16x8;
typedef __attribute__((ext_vector_type(4))) float f32x4;

#define DEV static __device__ __forceinline__

DEV float bf2f(u16 u) { unsigned v = ((unsigned)u) << 16; float f; __builtin_memcpy(&f, &v, 4); return f; }
DEV u16 f2bf(float f) {
  unsigned u; __builtin_memcpy(&u, &f, 4);
  unsigned lsb = (u >> 16) & 1;
  u += 0x7fffu + lsb;  // RNE
  return (u16)(u >> 16);
}
DEV float exp2fast(float x) { return __builtin_amdgcn_exp2f(x); }  // v_exp_f32
DEV f32x4 mfma16(short8 a, short8 b, f32x4 c) {
  return __builtin_amdgcn_mfma_f32_16x16x32_bf16(
      __builtin_bit_cast(bf16x8, a), __builtin_bit_cast(bf16x8, b), c, 0, 0, 0);
}
DEV short8 ld8(const u16* p) { return *(const short8*)p; }

// ---------------- fused weight prep (round-4 proven; output layout unchanged) ----------------
__global__ void prep_all(const float* __restrict__ hw, const float* __restrict__ wo,
                         const float* __restrict__ w1, const float* __restrict__ w2,
                         u16* __restrict__ wqh, u16* __restrict__ wql,
                         u16* __restrict__ woT, u16* __restrict__ w1T, u16* __restrict__ w2T) {
  int idx = blockIdx.x * 256 + threadIdx.x;
  if (idx < 786432) {  // 8*512*192
    int e = idx % 192;
    int d = (idx / 192) % 512;
    int h = idx / (192 * 512);
    float v = hw[idx];
    int n = (e < 64) ? (h * 64 + e) : (e < 128) ? (512 + h * 64 + e - 64) : (1024 + h * 64 + e - 128);
    size_t oi = (size_t)n * 512 + d;
    u16 hh = f2bf(v);
    wqh[oi] = hh;
    if (e < 128) wql[oi] = f2bf(v - bf2f(hh));
  } else if (idx < 786432 + 262144) {
    int i = idx - 786432;  // wo: K=512, N=512
    int n = i % 512, k = i / 512;
    woT[(size_t)n * 512 + k] = f2bf(wo[i]);
  } else if (idx < 786432 + 262144 + 65536) {
    int i = idx - (786432 + 262144);  // w1: K=512, N=128
    int n = i % 128, k = i / 128;
    w1T[(size_t)n * 512 + k] = f2bf(w1[i]);
  } else if (idx < 786432 + 262144 + 131072) {
    int i = idx - (786432 + 262144 + 65536);  // w2: K=128, N=512
    int n = i % 512, k = i / 512;
    w2T[(size_t)n * 128 + k] = f2bf(w2[i]);
  }
}

// ---------------- LayerNorm: f32 (rows x 512) -> bf16 hi/lo ----------------
__global__ __launch_bounds__(256) void ln_kernel(const float* __restrict__ in,
                                                 const float* __restrict__ w,
                                                 const float* __restrict__ bb,
                                                 u16* __restrict__ hi, u16* __restrict__ lo) {
  const int wv = threadIdx.x >> 6, lane = threadIdx.x & 63;
  const int row = blockIdx.x * 4 + wv;
  const float4* r = (const float4*)(in + (size_t)row * 512);
  float4 a0 = r[lane * 2], a1 = r[lane * 2 + 1];
  float s = a0.x + a0.y + a0.z + a0.w + a1.x + a1.y + a1.z + a1.w;
  float ss = a0.x * a0.x + a0.y * a0.y + a0.z * a0.z + a0.w * a0.w +
             a1.x * a1.x + a1.y * a1.y + a1.z * a1.z + a1.w * a1.w;
#pragma unroll
  for (int m = 1; m < 64; m <<= 1) { s += __shfl_xor(s, m); ss += __shfl_xor(ss, m); }
  float mu = s * (1.f / 512.f);
  float var = ss * (1.f / 512.f) - mu * mu;
  float rstd = rsqrtf(var + 1e-5f);
  const float4* wp = (const float4*)w + lane * 2;
  const float4* bp = (const float4*)bb + lane * 2;
  float4 w0 = wp[0], w1v = wp[1], b0 = bp[0], b1v = bp[1];
  float xv[8] = {a0.x, a0.y, a0.z, a0.w, a1.x, a1.y, a1.z, a1.w};
  float wv8[8] = {w0.x, w0.y, w0.z, w0.w, w1v.x, w1v.y, w1v.z, w1v.w};
  float bv8[8] = {b0.x, b0.y, b0.z, b0.w, b1v.x, b1v.y, b1v.z, b1v.w};
  short8 oh, ol;
#pragma unroll
  for (int i = 0; i < 8; i++) {
    float v = (xv[i] - mu) * rstd * wv8[i] + bv8[i];
    u16 hh = f2bf(v);
    oh[i] = (short)hh;
    ol[i] = (short)f2bf(v - bf2f(hh));
  }
  *(short8*)(hi + (size_t)row * 512 + lane * 8) = oh;
  *(short8*)(lo + (size_t)row * 512 + lane * 8) = ol;
}

// ---------------- QKV GEMM (r4 structure): BM=128, BN=64, grid (32,24) ----------------
__global__ __launch_bounds__(256) void gemm_qkv(const u16* __restrict__ Ah, const u16* __restrict__ Alo,
                                                const u16* __restrict__ Bh, const u16* __restrict__ Blo,
                                                u16* __restrict__ qkh, u16* __restrict__ qkl,
                                                u16* __restrict__ vT) {
  __shared__ __align__(16) u16 As[128][40], Asl[128][40], Bs[64][40], Bsl[64][40];
  const int tid = threadIdx.x, lane = tid & 63, wv = tid >> 6;
  const int wm = wv >> 1, wn = wv & 1, g = lane >> 4, r16 = lane & 15;
  const int bm = blockIdx.x * 128, bn = blockIdx.y * 64;
  const bool split = blockIdx.y < 16;
  short8 sA[2], sAl[2], sB, sBl;
  auto ldtile = [&](int kt) {
#pragma unroll
    for (int c = 0; c < 2; c++) {
      int ch = c * 256 + tid;
      sA[c] = ld8(Ah + (size_t)(bm + (ch >> 2)) * 512 + kt + (ch & 3) * 8);
      if (split) sAl[c] = ld8(Alo + (size_t)(bm + (ch >> 2)) * 512 + kt + (ch & 3) * 8);
    }
    sB = ld8(Bh + (size_t)(bn + (tid >> 2)) * 512 + kt + (tid & 3) * 8);
    if (split) sBl = ld8(Blo + (size_t)(bn + (tid >> 2)) * 512 + kt + (tid & 3) * 8);
  };
  f32x4 acc[4][2] = {};
  ldtile(0);
  for (int kt = 0; kt < 512; kt += 32) {
    __syncthreads();
#pragma unroll
    for (int c = 0; c < 2; c++) {
      int ch = c * 256 + tid;
      *(short8*)&As[ch >> 2][(ch & 3) * 8] = sA[c];
      if (split) *(short8*)&Asl[ch >> 2][(ch & 3) * 8] = sAl[c];
    }
    *(short8*)&Bs[tid >> 2][(tid & 3) * 8] = sB;
    if (split) *(short8*)&Bsl[tid >> 2][(tid & 3) * 8] = sBl;
    __syncthreads();
    if (kt + 32 < 512) ldtile(kt + 32);
    short8 af[4], bf_[2], afl[4], bfl[2];
#pragma unroll
    for (int mi = 0; mi < 4; mi++) af[mi] = *(const short8*)&As[wm * 64 + mi * 16 + r16][g * 8];
#pragma unroll
    for (int ni = 0; ni < 2; ni++) bf_[ni] = *(const short8*)&Bs[wn * 32 + ni * 16 + r16][g * 8];
    if (split) {
#pragma unroll
      for (int mi = 0; mi < 4; mi++) afl[mi] = *(const short8*)&Asl[wm * 64 + mi * 16 + r16][g * 8];
#pragma unroll
      for (int ni = 0; ni < 2; ni++) bfl[ni] = *(const short8*)&Bsl[wn * 32 + ni * 16 + r16][g * 8];
    }
#pragma unroll
    for (int mi = 0; mi < 4; mi++)
#pragma unroll
      for (int ni = 0; ni < 2; ni++) {
        acc[mi][ni] = mfma16(af[mi], bf_[ni], acc[mi][ni]);
        if (split) {
          acc[mi][ni] = mfma16(af[mi], bfl[ni], acc[mi][ni]);
          acc[mi][ni] = mfma16(afl[mi], bf_[ni], acc[mi][ni]);
        }
      }
  }
#pragma unroll
  for (int mi = 0; mi < 4; mi++)
#pragma unroll
    for (int ni = 0; ni < 2; ni++) {
      int col = bn + wn * 32 + ni * 16 + r16;
      int row0 = bm + wm * 64 + mi * 16 + g * 4;
      if (split) {
#pragma unroll
        for (int j = 0; j < 4; j++) {
          size_t oi = (size_t)(row0 + j) * 1024 + col;
          float v = acc[mi][ni][j];
          u16 hh = f2bf(v);
          qkh[oi] = hh;
          qkl[oi] = f2bf(v - bf2f(hh));
        }
      } else {
        int vcol = col - 1024;
        ushort4 pk;
        pk.x = f2bf(acc[mi][ni][0]);
        pk.y = f2bf(acc[mi][ni][1]);
        pk.z = f2bf(acc[mi][ni][2]);
        pk.w = f2bf(acc[mi][ni][3]);
        *(ushort4*)(vT + (size_t)vcol * 4096 + row0) = pk;
      }
    }
}

// ---------------- generic GEMM ----------------
template <int MF, int NF, int EPI>
__global__ __launch_bounds__(256) void gemm_g(const u16* __restrict__ A, const u16* __restrict__ BT,
                                              const float* __restrict__ res, const float* __restrict__ bias,
                                              u16* __restrict__ outb, float* __restrict__ outf,
                                              int N, int K) {
  constexpr int BM = 32 * MF, BN = 32 * NF;
  constexpr int CA = (BM * 4 + 255) / 256, CB = (BN * 4 + 255) / 256;
  __shared__ __align__(16) u16 As[BM][40], Bs[BN][40];
  const int tid = threadIdx.x, lane = tid & 63, wv = tid >> 6;
  const int wm = wv >> 1, wn = wv & 1, g = lane >> 4, r16 = lane & 15;
  const int bm = blockIdx.x * BM, bn = blockIdx.y * BN;
  short8 sA[CA], sB[CB];
  auto ldtile = [&](int kt) {
#pragma unroll
    for (int c = 0; c < CA; c++) {
      int ch = c * 256 + tid;
      if (ch < BM * 4) sA[c] = ld8(A + (size_t)(bm + (ch >> 2)) * K + kt + (ch & 3) * 8);
    }
#pragma unroll
    for (int c = 0; c < CB; c++) {
      int ch = c * 256 + tid;
      if (ch < BN * 4) sB[c] = ld8(BT + (size_t)(bn + (ch >> 2)) * K + kt + (ch & 3) * 8);
    }
  };
  f32x4 acc[MF][NF] = {};
  ldtile(0);
  for (int kt = 0; kt < K; kt += 32) {
    __syncthreads();
#pragma unroll
    for (int c = 0; c < CA; c++) {
      int ch = c * 256 + tid;
      if (ch < BM * 4) *(short8*)&As[ch >> 2][(ch & 3) * 8] = sA[c];
    }
#pragma unroll
    for (int c = 0; c < CB; c++) {
      int ch = c * 256 + tid;
      if (ch < BN * 4) *(short8*)&Bs[ch >> 2][(ch & 3) * 8] = sB[c];
    }
    __syncthreads();
    if (kt + 32 < K) ldtile(kt + 32);
    short8 af[MF], bf_[NF];
#pragma unroll
    for (int mi = 0; mi < MF; mi++) af[mi] = *(const short8*)&As[wm * 16 * MF + mi * 16 + r16][g * 8];
#pragma unroll
    for (int ni = 0; ni < NF; ni++) bf_[ni] = *(const short8*)&Bs[wn * 16 * NF + ni * 16 + r16][g * 8];
#pragma unroll
    for (int mi = 0; mi < MF; mi++)
#pragma unroll
      for (int ni = 0; ni < NF; ni++) acc[mi][ni] = mfma16(af[mi], bf_[ni], acc[mi][ni]);
  }
#pragma unroll
  for (int mi = 0; mi < MF; mi++)
#pragma unroll
    for (int ni = 0; ni < NF; ni++) {
      int col = bn + wn * 16 * NF + ni * 16 + r16;
      int row0 = bm + wm * 16 * MF + mi * 16 + g * 4;
#pragma unroll
      for (int j = 0; j < 4; j++) {
        size_t oi = (size_t)(row0 + j) * N + col;
        float v = acc[mi][ni][j];
        if (EPI == 1) {
          outf[oi] = v + res[oi];
        } else if (EPI == 2) {
          outb[oi] = f2bf(v + bias[col]);
        } else {
          float u = v + bias[col];
          float gl = 0.5f * u * (1.0f + erff(u * 0.70710678118f));
          outf[oi] = gl + res[oi];
        }
      }
    }
}

// ---------------- flash attention v10: 2 waves x 32 q-rows, swapped QK^T, in-reg softmax ----------------
// 128 threads; grid (32,16) = 512 blocks (2/CU). Each wave owns 32 q-rows as two 16-row frags (t=0,1).
// K/V fragment reads are shared across t (6 MFMA per K-read, 2 per V-read) -> ~45% less LDS traffic/row.
__global__ __launch_bounds__(128, 2) void attn_kernel(const u16* __restrict__ qkh,
                                                      const u16* __restrict__ qkl,
                                                      const u16* __restrict__ vT,
                                                      u16* __restrict__ o) {
  constexpr int SK = 72, SV = 136, SP = 136;
  __shared__ __align__(16) u16 Kh[128 * SK], Kl[128 * SK], Vt[64 * SV];
  __shared__ __align__(16) u16 Pl[2][32 * SP];
  const int tid = threadIdx.x, lane = tid & 63, w = tid >> 6;  // w = 0,1
  const int g = lane >> 4, r16 = lane & 15;
  const int qb = blockIdx.x * 64;
  const int b = blockIdx.y >> 3, h = blockIdx.y & 7;
  const size_t bbase = (size_t)b * 2048 * 1024;
  const u16* Qh = qkh + bbase + h * 64;
  const u16* Ql = qkl + bbase + h * 64;
  const u16* KgH = qkh + bbase + 512 + h * 64;
  const u16* KgL = qkl + bbase + 512 + h * 64;
  const u16* Vtg = vT + (size_t)h * 64 * 4096 + (size_t)b * 2048;  // row d (0..63), col kv

  // Q fragments for two 16-row tiles: rows qb + w*32 + t*16 + r16
  short8 qh[2][2], qlo[2][2];
#pragma unroll
  for (int t = 0; t < 2; t++) {
    int qrow = qb + w * 32 + t * 16 + r16;
#pragma unroll
    for (int ks = 0; ks < 2; ks++) {
      qh[t][ks] = ld8(Qh + (size_t)qrow * 1024 + ks * 32 + g * 8);
      qlo[t][ks] = ld8(Ql + (size_t)qrow * 1024 + ks * 32 + g * 8);
    }
  }

  f32x4 oacc[2][4] = {};
  float m_r[2] = {-3e38f, -3e38f}, l_r[2] = {0.f, 0.f};

  // staging (128 threads): K 128 rows x 8 chunks, V 64 rows x 16 chunks; 8 chunks/thread each.
  short8 kA[8], kB[8], vS[8];
  auto ldkv = [&](int kt) {
#pragma unroll
    for (int c = 0; c < 8; c++) {
      int kr = c * 16 + (tid >> 3), kc = (tid & 7) * 8;
      kA[c] = ld8(KgH + (size_t)(kt + kr) * 1024 + kc);
      kB[c] = ld8(KgL + (size_t)(kt + kr) * 1024 + kc);
    }
#pragma unroll
    for (int c = 0; c < 8; c++) {
      int vd = c * 8 + (tid >> 4), vc = (tid & 15) * 8;
      vS[c] = ld8(Vtg + (size_t)vd * 4096 + kt + vc);
    }
  };
  ldkv(0);

  for (int kt = 0; kt < 2048; kt += 128) {
    __syncthreads();
#pragma unroll
    for (int c = 0; c < 8; c++) {
      int kr = c * 16 + (tid >> 3), kc = (tid & 7) * 8;
      *(short8*)&Kh[kr * SK + kc] = kA[c];
      *(short8*)&Kl[kr * SK + kc] = kB[c];
    }
#pragma unroll
    for (int c = 0; c < 8; c++) {
      int vd = c * 8 + (tid >> 4), vc = (tid & 15) * 8;
      *(short8*)&Vt[vd * SV + vc] = vS[c];
    }
    __syncthreads();
    if (kt + 128 < 2048) ldkv(kt + 128);
    // ---- QK^T swapped; each K-fragment read serves both t ----
    f32x4 s[2][8];
#pragma unroll
    for (int t = 0; t < 2; t++)
#pragma unroll
      for (int f = 0; f < 8; f++) s[t][f] = f32x4{0.f, 0.f, 0.f, 0.f};
#pragma unroll
    for (int f = 0; f < 8; f++) {
      int krow = f * 16 + r16;
#pragma unroll
      for (int ks = 0; ks < 2; ks++) {
        short8 bh = *(const short8*)&Kh[krow * SK + ks * 32 + g * 8];
        short8 bl = *(const short8*)&Kl[krow * SK + ks * 32 + g * 8];
#pragma unroll
        for (int t = 0; t < 2; t++) {
          s[t][f] = mfma16(bh, qh[t][ks], s[t][f]);
          s[t][f] = mfma16(bl, qh[t][ks], s[t][f]);
          s[t][f] = mfma16(bh, qlo[t][ks], s[t][f]);
        }
      }
    }
    // ---- in-register online softmax per t (lane owns q-row t*16+r16) ----
    constexpr float SCL2 = 0.125f * 1.44269504f;
    float scl[2];
#pragma unroll
    for (int t = 0; t < 2; t++) {
      float a[8][4];
      float vm = -3e38f;
#pragma unroll
      for (int f = 0; f < 8; f++)
#pragma unroll
        for (int r = 0; r < 4; r++) {
          a[f][r] = s[t][f][r] * SCL2;
          vm = fmaxf(vm, a[f][r]);
        }
      vm = fmaxf(vm, __shfl_xor(vm, 16));
      vm = fmaxf(vm, __shfl_xor(vm, 32));
      float mn = fmaxf(m_r[t], vm);
      scl[t] = exp2fast(m_r[t] - mn);
      m_r[t] = mn;
      float rs = 0.f;
#pragma unroll
      for (int f = 0; f < 8; f++) {
        float e0 = exp2fast(a[f][0] - mn), e1 = exp2fast(a[f][1] - mn);
        float e2 = exp2fast(a[f][2] - mn), e3 = exp2fast(a[f][3] - mn);
        rs += (e0 + e1) + (e2 + e3);
        u32 u0, u1, u2, u3;
        __builtin_memcpy(&u0, &e0, 4);
        __builtin_memcpy(&u1, &e1, 4);
        __builtin_memcpy(&u2, &e2, 4);
        __builtin_memcpy(&u3, &e3, 4);
        uint2 pk;
        pk.x = (u0 >> 16) | (u1 & 0xFFFF0000u);
        pk.y = (u2 >> 16) | (u3 & 0xFFFF0000u);
        *(uint2*)&Pl[w][(t * 16 + r16) * SP + f * 16 + g * 4] = pk;
      }
      rs += __shfl_xor(rs, 16);
      rs += __shfl_xor(rs, 32);
      l_r[t] = l_r[t] * scl[t] + rs;
    }
    // rescale oacc rows (row j of frag t scaled by scl[t] owned at lanes r16 == g*4+j)
#pragma unroll
    for (int t = 0; t < 2; t++)
#pragma unroll
      for (int j = 0; j < 4; j++) {
        float sj = __shfl(scl[t], (g << 4) + (g << 2) + j);
#pragma unroll
        for (int dt = 0; dt < 4; dt++) oacc[t][dt][j] *= sj;
      }
    // ---- P@V: each V-fragment read serves both t ----
#pragma unroll
    for (int ks = 0; ks < 4; ks++) {
      short8 pa0 = *(const short8*)&Pl[w][(0 * 16 + r16) * SP + ks * 32 + g * 8];
      short8 pa1 = *(const short8*)&Pl[w][(1 * 16 + r16) * SP + ks * 32 + g * 8];
#pragma unroll
      for (int dt = 0; dt < 4; dt++) {
        short8 vb = *(const short8*)&Vt[(dt * 16 + r16) * SV + ks * 32 + g * 8];
        oacc[0][dt] = mfma16(pa0, vb, oacc[0][dt]);
        oacc[1][dt] = mfma16(pa1, vb, oacc[1][dt]);
      }
    }
  }
  // epilogue per t
#pragma unroll
  for (int t = 0; t < 2; t++)
#pragma unroll
    for (int j = 0; j < 4; j++) {
      float lj = __shfl(l_r[t], (g << 4) + (g << 2) + j);
      float il = 1.f / lj;
      int row = b * 2048 + qb + w * 32 + t * 16 + g * 4 + j;
#pragma unroll
      for (int dt = 0; dt < 4; dt++) {
        int col = h * 64 + dt * 16 + r16;
        o[(size_t)row * 512 + col] = f2bf(oacc[t][dt][j] * il);
      }
    }
}

// ---------------- launcher ----------------
extern "C" void kernel_launch(void* const* d_in, const int* in_sizes, int n_in,
                              void* d_out, int out_size, void* d_ws, size_t ws_size,
                              hipStream_t stream) {
  const float* z = (const float*)d_in[0];
  const float* head_w = (const float*)d_in[1];
  const float* w_o = (const float*)d_in[2];
  const float* ln_w = (const float*)d_in[3];
  const float* ln_b = (const float*)d_in[4];
  const float* w1 = (const float*)d_in[5];
  const float* b1 = (const float*)d_in[6];
  const float* w2 = (const float*)d_in[7];
  const float* b2 = (const float*)d_in[8];
  float* out = (float*)d_out;

  size_t off = 0;
  auto alc = [&](size_t n) {
    void* p = (char*)d_ws + off;
    off += (n + 255) & ~(size_t)255;
    return p;
  };
  u16* x_hi = (u16*)alc((size_t)4096 * 512 * 2);
  u16* x_lo = (u16*)alc((size_t)4096 * 512 * 2);
  u16* wqh = (u16*)alc((size_t)1536 * 512 * 2);
  u16* wql = (u16*)alc((size_t)1536 * 512 * 2);
  u16* woT = (u16*)alc((size_t)512 * 512 * 2);
  u16* w1T = (u16*)alc((size_t)128 * 512 * 2);
  u16* w2T = (u16*)alc((size_t)512 * 128 * 2);
  u16* qkh = (u16*)alc((size_t)4096 * 1024 * 2);
  u16* qkl = (u16*)alc((size_t)4096 * 1024 * 2);
  u16* vT = (u16*)alc((size_t)512 * 4096 * 2);
  u16* ob = (u16*)alc((size_t)4096 * 512 * 2);
  float* z2 = (float*)alc((size_t)4096 * 512 * 4);
  u16* tb = (u16*)alc((size_t)4096 * 128 * 2);

  prep_all<<<4608, 256, 0, stream>>>(head_w, w_o, w1, w2, wqh, wql, woT, w1T, w2T);

  // LN1: z -> x hi/lo
  ln_kernel<<<1024, 256, 0, stream>>>(z, ln_w, ln_b, x_hi, x_lo);

  // QKV projection (r4 tiling); V written transposed to vT
  gemm_qkv<<<dim3(32, 24), 256, 0, stream>>>(x_hi, x_lo, wqh, wql, qkh, qkl, vT);

  // flash attention (2 waves x 32 q-rows, shared K/V fragment reads)
  attn_kernel<<<dim3(32, 16), 128, 0, stream>>>(qkh, qkl, vT, ob);

  // z2 = o @ w_o + z
  gemm_g<2, 2, 1><<<dim3(64, 8), 256, 0, stream>>>(ob, woT, z, nullptr, nullptr, z2, 512, 512);

  // LN2
  ln_kernel<<<1024, 256, 0, stream>>>(z2, ln_w, ln_b, x_hi, x_lo);

  // t = y @ w1 + b1
  gemm_g<1, 2, 2><<<dim3(128, 2), 256, 0, stream>>>(x_hi, w1T, nullptr, b1, tb, nullptr, 128, 512);

  // out = gelu(t @ w2 + b2) + z2
  gemm_g<2, 2, 3><<<dim3(64, 8), 256, 0, stream>>>(tb, w2T, z2, b2, nullptr, out, 512, 128);
}

// Round 15
// 132.338 us; speedup vs baseline: 1.0523x; 1.0523x over previous
//
#include <hip/hip_runtime.h>
#include <hip/hip_bf16.h>

typedef unsigned short u16;
typedef unsigned int u32;
typedef __attribute__((ext_vector_type(8))) short short8;
typedef __attribute__((ext_vector_type(8))) __bf16 bf16x8;
typedef __attribute__((ext_vector_type(4))) float f32x4;

#define DEV static __device__ __forceinline__

DEV float bf2f(u16 u) { unsigned v = ((unsigned)u) << 16; float f; __builtin_memcpy(&f, &v, 4); return f; }
DEV u16 f2bf(float f) {
  unsigned u; __builtin_memcpy(&u, &f, 4);
  unsigned lsb = (u >> 16) & 1;
  u += 0x7fffu + lsb;  // RNE
  return (u16)(u >> 16);
}
DEV float exp2fast(float x) { return __builtin_amdgcn_exp2f(x); }  // v_exp_f32
DEV f32x4 mfma16(short8 a, short8 b, f32x4 c) {
  return __builtin_amdgcn_mfma_f32_16x16x32_bf16(
      __builtin_bit_cast(bf16x8, a), __builtin_bit_cast(bf16x8, b), c, 0, 0, 0);
}
DEV short8 ld8(const u16* p) { return *(const short8*)p; }

// ---------------- fused weight prep (round-4 proven; output layout unchanged) ----------------
__global__ void prep_all(const float* __restrict__ hw, const float* __restrict__ wo,
                         const float* __restrict__ w1, const float* __restrict__ w2,
                         u16* __restrict__ wqh, u16* __restrict__ wql,
                         u16* __restrict__ woT, u16* __restrict__ w1T, u16* __restrict__ w2T) {
  int idx = blockIdx.x * 256 + threadIdx.x;
  if (idx < 786432) {  // 8*512*192
    int e = idx % 192;
    int d = (idx / 192) % 512;
    int h = idx / (192 * 512);
    float v = hw[idx];
    int n = (e < 64) ? (h * 64 + e) : (e < 128) ? (512 + h * 64 + e - 64) : (1024 + h * 64 + e - 128);
    size_t oi = (size_t)n * 512 + d;
    u16 hh = f2bf(v);
    wqh[oi] = hh;
    if (e < 128) wql[oi] = f2bf(v - bf2f(hh));
  } else if (idx < 786432 + 262144) {
    int i = idx - 786432;  // wo: K=512, N=512
    int n = i % 512, k = i / 512;
    woT[(size_t)n * 512 + k] = f2bf(wo[i]);
  } else if (idx < 786432 + 262144 + 65536) {
    int i = idx - (786432 + 262144);  // w1: K=512, N=128
    int n = i % 128, k = i / 128;
    w1T[(size_t)n * 512 + k] = f2bf(w1[i]);
  } else if (idx < 786432 + 262144 + 131072) {
    int i = idx - (786432 + 262144 + 65536);  // w2: K=128, N=512
    int n = i % 512, k = i / 512;
    w2T[(size_t)n * 128 + k] = f2bf(w2[i]);
  }
}

// ---------------- LayerNorm: f32 (rows x 512) -> bf16 hi/lo ----------------
__global__ __launch_bounds__(256) void ln_kernel(const float* __restrict__ in,
                                                 const float* __restrict__ w,
                                                 const float* __restrict__ bb,
                                                 u16* __restrict__ hi, u16* __restrict__ lo) {
  const int wv = threadIdx.x >> 6, lane = threadIdx.x & 63;
  const int row = blockIdx.x * 4 + wv;
  const float4* r = (const float4*)(in + (size_t)row * 512);
  float4 a0 = r[lane * 2], a1 = r[lane * 2 + 1];
  float s = a0.x + a0.y + a0.z + a0.w + a1.x + a1.y + a1.z + a1.w;
  float ss = a0.x * a0.x + a0.y * a0.y + a0.z * a0.z + a0.w * a0.w +
             a1.x * a1.x + a1.y * a1.y + a1.z * a1.z + a1.w * a1.w;
#pragma unroll
  for (int m = 1; m < 64; m <<= 1) { s += __shfl_xor(s, m); ss += __shfl_xor(ss, m); }
  float mu = s * (1.f / 512.f);
  float var = ss * (1.f / 512.f) - mu * mu;
  float rstd = rsqrtf(var + 1e-5f);
  const float4* wp = (const float4*)w + lane * 2;
  const float4* bp = (const float4*)bb + lane * 2;
  float4 w0 = wp[0], w1v = wp[1], b0 = bp[0], b1v = bp[1];
  float xv[8] = {a0.x, a0.y, a0.z, a0.w, a1.x, a1.y, a1.z, a1.w};
  float wv8[8] = {w0.x, w0.y, w0.z, w0.w, w1v.x, w1v.y, w1v.z, w1v.w};
  float bv8[8] = {b0.x, b0.y, b0.z, b0.w, b1v.x, b1v.y, b1v.z, b1v.w};
  short8 oh, ol;
#pragma unroll
  for (int i = 0; i < 8; i++) {
    float v = (xv[i] - mu) * rstd * wv8[i] + bv8[i];
    u16 hh = f2bf(v);
    oh[i] = (short)hh;
    ol[i] = (short)f2bf(v - bf2f(hh));
  }
  *(short8*)(hi + (size_t)row * 512 + lane * 8) = oh;
  *(short8*)(lo + (size_t)row * 512 + lane * 8) = ol;
}

// ---------------- QKV GEMM (r4 structure): BM=128, BN=64, grid (32,24) ----------------
__global__ __launch_bounds__(256) void gemm_qkv(const u16* __restrict__ Ah, const u16* __restrict__ Alo,
                                                const u16* __restrict__ Bh, const u16* __restrict__ Blo,
                                                u16* __restrict__ qkh, u16* __restrict__ qkl,
                                                u16* __restrict__ vT) {
  __shared__ __align__(16) u16 As[128][40], Asl[128][40], Bs[64][40], Bsl[64][40];
  const int tid = threadIdx.x, lane = tid & 63, wv = tid >> 6;
  const int wm = wv >> 1, wn = wv & 1, g = lane >> 4, r16 = lane & 15;
  const int bm = blockIdx.x * 128, bn = blockIdx.y * 64;
  const bool split = blockIdx.y < 16;
  short8 sA[2], sAl[2], sB, sBl;
  auto ldtile = [&](int kt) {
#pragma unroll
    for (int c = 0; c < 2; c++) {
      int ch = c * 256 + tid;
      sA[c] = ld8(Ah + (size_t)(bm + (ch >> 2)) * 512 + kt + (ch & 3) * 8);
      if (split) sAl[c] = ld8(Alo + (size_t)(bm + (ch >> 2)) * 512 + kt + (ch & 3) * 8);
    }
    sB = ld8(Bh + (size_t)(bn + (tid >> 2)) * 512 + kt + (tid & 3) * 8);
    if (split) sBl = ld8(Blo + (size_t)(bn + (tid >> 2)) * 512 + kt + (tid & 3) * 8);
  };
  f32x4 acc[4][2] = {};
  ldtile(0);
  for (int kt = 0; kt < 512; kt += 32) {
    __syncthreads();
#pragma unroll
    for (int c = 0; c < 2; c++) {
      int ch = c * 256 + tid;
      *(short8*)&As[ch >> 2][(ch & 3) * 8] = sA[c];
      if (split) *(short8*)&Asl[ch >> 2][(ch & 3) * 8] = sAl[c];
    }
    *(short8*)&Bs[tid >> 2][(tid & 3) * 8] = sB;
    if (split) *(short8*)&Bsl[tid >> 2][(tid & 3) * 8] = sBl;
    __syncthreads();
    if (kt + 32 < 512) ldtile(kt + 32);
    short8 af[4], bf_[2], afl[4], bfl[2];
#pragma unroll
    for (int mi = 0; mi < 4; mi++) af[mi] = *(const short8*)&As[wm * 64 + mi * 16 + r16][g * 8];
#pragma unroll
    for (int ni = 0; ni < 2; ni++) bf_[ni] = *(const short8*)&Bs[wn * 32 + ni * 16 + r16][g * 8];
    if (split) {
#pragma unroll
      for (int mi = 0; mi < 4; mi++) afl[mi] = *(const short8*)&Asl[wm * 64 + mi * 16 + r16][g * 8];
#pragma unroll
      for (int ni = 0; ni < 2; ni++) bfl[ni] = *(const short8*)&Bsl[wn * 32 + ni * 16 + r16][g * 8];
    }
#pragma unroll
    for (int mi = 0; mi < 4; mi++)
#pragma unroll
      for (int ni = 0; ni < 2; ni++) {
        acc[mi][ni] = mfma16(af[mi], bf_[ni], acc[mi][ni]);
        if (split) {
          acc[mi][ni] = mfma16(af[mi], bfl[ni], acc[mi][ni]);
          acc[mi][ni] = mfma16(afl[mi], bf_[ni], acc[mi][ni]);
        }
      }
  }
#pragma unroll
  for (int mi = 0; mi < 4; mi++)
#pragma unroll
    for (int ni = 0; ni < 2; ni++) {
      int col = bn + wn * 32 + ni * 16 + r16;
      int row0 = bm + wm * 64 + mi * 16 + g * 4;
      if (split) {
#pragma unroll
        for (int j = 0; j < 4; j++) {
          size_t oi = (size_t)(row0 + j) * 1024 + col;
          float v = acc[mi][ni][j];
          u16 hh = f2bf(v);
          qkh[oi] = hh;
          qkl[oi] = f2bf(v - bf2f(hh));
        }
      } else {
        int vcol = col - 1024;
        ushort4 pk;
        pk.x = f2bf(acc[mi][ni][0]);
        pk.y = f2bf(acc[mi][ni][1]);
        pk.z = f2bf(acc[mi][ni][2]);
        pk.w = f2bf(acc[mi][ni][3]);
        *(ushort4*)(vT + (size_t)vcol * 4096 + row0) = pk;
      }
    }
}

// ---------------- generic GEMM ----------------
template <int MF, int NF, int EPI>
__global__ __launch_bounds__(256) void gemm_g(const u16* __restrict__ A, const u16* __restrict__ BT,
                                              const float* __restrict__ res, const float* __restrict__ bias,
                                              u16* __restrict__ outb, float* __restrict__ outf,
                                              int N, int K) {
  constexpr int BM = 32 * MF, BN = 32 * NF;
  constexpr int CA = (BM * 4 + 255) / 256, CB = (BN * 4 + 255) / 256;
  __shared__ __align__(16) u16 As[BM][40], Bs[BN][40];
  const int tid = threadIdx.x, lane = tid & 63, wv = tid >> 6;
  const int wm = wv >> 1, wn = wv & 1, g = lane >> 4, r16 = lane & 15;
  const int bm = blockIdx.x * BM, bn = blockIdx.y * BN;
  short8 sA[CA], sB[CB];
  auto ldtile = [&](int kt) {
#pragma unroll
    for (int c = 0; c < CA; c++) {
      int ch = c * 256 + tid;
      if (ch < BM * 4) sA[c] = ld8(A + (size_t)(bm + (ch >> 2)) * K + kt + (ch & 3) * 8);
    }
#pragma unroll
    for (int c = 0; c < CB; c++) {
      int ch = c * 256 + tid;
      if (ch < BN * 4) sB[c] = ld8(BT + (size_t)(bn + (ch >> 2)) * K + kt + (ch & 3) * 8);
    }
  };
  f32x4 acc[MF][NF] = {};
  ldtile(0);
  for (int kt = 0; kt < K; kt += 32) {
    __syncthreads();
#pragma unroll
    for (int c = 0; c < CA; c++) {
      int ch = c * 256 + tid;
      if (ch < BM * 4) *(short8*)&As[ch >> 2][(ch & 3) * 8] = sA[c];
    }
#pragma unroll
    for (int c = 0; c < CB; c++) {
      int ch = c * 256 + tid;
      if (ch < BN * 4) *(short8*)&Bs[ch >> 2][(ch & 3) * 8] = sB[c];
    }
    __syncthreads();
    if (kt + 32 < K) ldtile(kt + 32);
    short8 af[MF], bf_[NF];
#pragma unroll
    for (int mi = 0; mi < MF; mi++) af[mi] = *(const short8*)&As[wm * 16 * MF + mi * 16 + r16][g * 8];
#pragma unroll
    for (int ni = 0; ni < NF; ni++) bf_[ni] = *(const short8*)&Bs[wn * 16 * NF + ni * 16 + r16][g * 8];
#pragma unroll
    for (int mi = 0; mi < MF; mi++)
#pragma unroll
      for (int ni = 0; ni < NF; ni++) acc[mi][ni] = mfma16(af[mi], bf_[ni], acc[mi][ni]);
  }
#pragma unroll
  for (int mi = 0; mi < MF; mi++)
#pragma unroll
    for (int ni = 0; ni < NF; ni++) {
      int col = bn + wn * 16 * NF + ni * 16 + r16;
      int row0 = bm + wm * 16 * MF + mi * 16 + g * 4;
#pragma unroll
      for (int j = 0; j < 4; j++) {
        size_t oi = (size_t)(row0 + j) * N + col;
        float v = acc[mi][ni][j];
        if (EPI == 1) {
          outf[oi] = v + res[oi];
        } else if (EPI == 2) {
          outb[oi] = f2bf(v + bias[col]);
        } else {
          float u = v + bias[col];
          float gl = 0.5f * u * (1.0f + erff(u * 0.70710678118f));
          outf[oi] = gl + res[oi];
        }
      }
    }
}

// ---------------- flash attention v11: 4 waves = 2 qg x 2 kv-half, t-sharing, swapped QK^T ----------------
// 256 threads, grid (32,16) = 512 blocks (2/CU -> 8 waves/CU = 2/SIMD).
// wave w: qg = w&1 owns q-rows qb+qg*32..+31 (frags t=0,1); half = w>>1 owns kv [half*1024,+1024), KVBLK=64.
// K-frag reads serve 6 MFMA (2t x 3 split); V reads serve 2. In-LDS merge of halves at end (r9 formula).
__global__ __launch_bounds__(256) void attn_kernel(const u16* __restrict__ qkh,
                                                   const u16* __restrict__ qkl,
                                                   const u16* __restrict__ vT,
                                                   u16* __restrict__ o) {
  // u16 pool: Kh[128][72] @0 (rows 0-63 half0, 64-127 half1) | Kl @9216 | Vt[128][72] @18432
  // | Pl[w][32][72] @27648+w*2304. Total 36864 u16 = 73728 B.
  // Post-loop aliases (barrier-protected, inside Kh/Kl): oex f32[2qg][2t][16][64] @u16 0 (16KB);
  // mlx float2[2qg][2t][16] @u16 8192 (512B).
  __shared__ __align__(16) u16 smem[36864];
  u16* Kh = smem;
  u16* Kl = smem + 9216;
  u16* Vt = smem + 18432;
  const int tid = threadIdx.x, lane = tid & 63, w = tid >> 6;
  const int qg = w & 1, half = w >> 1;
  const int g = lane >> 4, r16 = lane & 15;
  u16* Pw = smem + 27648 + w * 2304;
  const int qb = blockIdx.x * 64;
  const int b = blockIdx.y >> 3, h = blockIdx.y & 7;
  const size_t bbase = (size_t)b * 2048 * 1024;
  const u16* Qh = qkh + bbase + h * 64;
  const u16* Ql = qkl + bbase + h * 64;
  const u16* KgH = qkh + bbase + 512 + h * 64;
  const u16* KgL = qkl + bbase + 512 + h * 64;
  const u16* Vtg = vT + (size_t)h * 64 * 4096 + (size_t)b * 2048;  // [d][kv]

  short8 qh[2][2], qlo[2][2];
#pragma unroll
  for (int t = 0; t < 2; t++) {
    int qrow = qb + qg * 32 + t * 16 + r16;
#pragma unroll
    for (int ks = 0; ks < 2; ks++) {
      qh[t][ks] = ld8(Qh + (size_t)qrow * 1024 + ks * 32 + g * 8);
      qlo[t][ks] = ld8(Ql + (size_t)qrow * 1024 + ks * 32 + g * 8);
    }
  }

  f32x4 oacc[2][4] = {};
  float m_r[2] = {-3e38f, -3e38f}, l_r[2] = {0.f, 0.f};

  // staging (256 threads, both halves): K 128 rows (64/half) x 8 chunks; V 128 (d,half) rows x 8 chunks.
  short8 kA[4], kB[4], vS[4];
  auto ldkv = [&](int kt) {  // kt in [0,1024)
#pragma unroll
    for (int c = 0; c < 4; c++) {
      int ch = c * 256 + tid;
      int kr = ch >> 3, kc = (ch & 7) * 8;
      int grow = kt + (kr & 63) + (kr >> 6) * 1024;
      kA[c] = ld8(KgH + (size_t)grow * 1024 + kc);
      kB[c] = ld8(KgL + (size_t)grow * 1024 + kc);
    }
#pragma unroll
    for (int c = 0; c < 4; c++) {
      int ch = c * 256 + tid;
      int vr = ch >> 3, vc = (ch & 7) * 8;  // vr: half=vr>>6, d=vr&63
      vS[c] = ld8(Vtg + (size_t)(vr & 63) * 4096 + kt + (vr >> 6) * 1024 + vc);
    }
  };
  ldkv(0);

  for (int kt = 0; kt < 1024; kt += 64) {
    __syncthreads();
#pragma unroll
    for (int c = 0; c < 4; c++) {
      int ch = c * 256 + tid;
      int kr = ch >> 3, kc = (ch & 7) * 8;
      *(short8*)&Kh[kr * 72 + kc] = kA[c];
      *(short8*)&Kl[kr * 72 + kc] = kB[c];
    }
#pragma unroll
    for (int c = 0; c < 4; c++) {
      int ch = c * 256 + tid;
      int vr = ch >> 3, vc = (ch & 7) * 8;
      *(short8*)&Vt[vr * 72 + vc] = vS[c];
    }
    __syncthreads();
    if (kt + 64 < 1024) ldkv(kt + 64);
    // ---- QK^T swapped; K-frag shared across t ----
    f32x4 s[2][4];
#pragma unroll
    for (int t = 0; t < 2; t++)
#pragma unroll
      for (int f = 0; f < 4; f++) s[t][f] = f32x4{0.f, 0.f, 0.f, 0.f};
#pragma unroll
    for (int f = 0; f < 4; f++) {
      int krow = half * 64 + f * 16 + r16;
#pragma unroll
      for (int ks = 0; ks < 2; ks++) {
        short8 bh = *(const short8*)&Kh[krow * 72 + ks * 32 + g * 8];
        short8 bl = *(const short8*)&Kl[krow * 72 + ks * 32 + g * 8];
#pragma unroll
        for (int t = 0; t < 2; t++) {
          s[t][f] = mfma16(bh, qh[t][ks], s[t][f]);
          s[t][f] = mfma16(bl, qh[t][ks], s[t][f]);
          s[t][f] = mfma16(bh, qlo[t][ks], s[t][f]);
        }
      }
    }
    // ---- in-register online softmax per t (lane owns q-row t*16+r16 of this qg) ----
    constexpr float SCL2 = 0.125f * 1.44269504f;
    float scl[2];
#pragma unroll
    for (int t = 0; t < 2; t++) {
      float a[4][4];
      float vm = -3e38f;
#pragma unroll
      for (int f = 0; f < 4; f++)
#pragma unroll
        for (int r = 0; r < 4; r++) {
          a[f][r] = s[t][f][r] * SCL2;
          vm = fmaxf(vm, a[f][r]);
        }
      vm = fmaxf(vm, __shfl_xor(vm, 16));
      vm = fmaxf(vm, __shfl_xor(vm, 32));
      float mn = fmaxf(m_r[t], vm);
      scl[t] = exp2fast(m_r[t] - mn);
      m_r[t] = mn;
      float rs = 0.f;
#pragma unroll
      for (int f = 0; f < 4; f++) {
        float e0 = exp2fast(a[f][0] - mn), e1 = exp2fast(a[f][1] - mn);
        float e2 = exp2fast(a[f][2] - mn), e3 = exp2fast(a[f][3] - mn);
        rs += (e0 + e1) + (e2 + e3);
        u32 u0, u1, u2, u3;
        __builtin_memcpy(&u0, &e0, 4);
        __builtin_memcpy(&u1, &e1, 4);
        __builtin_memcpy(&u2, &e2, 4);
        __builtin_memcpy(&u3, &e3, 4);
        uint2 pk;
        pk.x = (u0 >> 16) | (u1 & 0xFFFF0000u);
        pk.y = (u2 >> 16) | (u3 & 0xFFFF0000u);
        *(uint2*)&Pw[(t * 16 + r16) * 72 + f * 16 + g * 4] = pk;
      }
      rs += __shfl_xor(rs, 16);
      rs += __shfl_xor(rs, 32);
      l_r[t] = l_r[t] * scl[t] + rs;
    }
#pragma unroll
    for (int t = 0; t < 2; t++)
#pragma unroll
      for (int j = 0; j < 4; j++) {
        float sj = __shfl(scl[t], (g << 4) + (g << 2) + j);
#pragma unroll
        for (int dt = 0; dt < 4; dt++) oacc[t][dt][j] *= sj;
      }
    // ---- P@V: V-frag shared across t ----
#pragma unroll
    for (int ks = 0; ks < 2; ks++) {
      short8 pa0 = *(const short8*)&Pw[(0 * 16 + r16) * 72 + ks * 32 + g * 8];
      short8 pa1 = *(const short8*)&Pw[(1 * 16 + r16) * 72 + ks * 32 + g * 8];
#pragma unroll
      for (int dt = 0; dt < 4; dt++) {
        short8 vb = *(const short8*)&Vt[(half * 64 + dt * 16 + r16) * 72 + ks * 32 + g * 8];
        oacc[0][dt] = mfma16(pa0, vb, oacc[0][dt]);
        oacc[1][dt] = mfma16(pa1, vb, oacc[1][dt]);
      }
    }
  }
  // ---- in-block merge of kv halves (r9 formula; lane-owned m/l) ----
  __syncthreads();
  float* oex = (float*)smem;                    // [(qg*2+t)*16 + row][64]
  float2* mlx = (float2*)(smem + 8192);         // [(qg*2+t)*16 + row]
  if (half == 1) {
#pragma unroll
    for (int t = 0; t < 2; t++) {
#pragma unroll
      for (int dt = 0; dt < 4; dt++)
#pragma unroll
        for (int j = 0; j < 4; j++)
          oex[((qg * 2 + t) * 16 + g * 4 + j) * 64 + dt * 16 + r16] = oacc[t][dt][j];
      if (g == 0) mlx[(qg * 2 + t) * 16 + r16] = make_float2(m_r[t], l_r[t]);
    }
  }
  __syncthreads();
  if (half == 0) {
#pragma unroll
    for (int t = 0; t < 2; t++)
#pragma unroll
      for (int j = 0; j < 4; j++) {
        int rr = g * 4 + j;
        float m0 = __shfl(m_r[t], (g << 4) + (g << 2) + j);
        float l0 = __shfl(l_r[t], (g << 4) + (g << 2) + j);
        float2 ml1 = mlx[(qg * 2 + t) * 16 + rr];
        float mm = fmaxf(m0, ml1.x);
        float c0 = exp2fast(m0 - mm), c1 = exp2fast(ml1.x - mm);
        float inv = 1.f / (c0 * l0 + c1 * ml1.y);
        c0 *= inv;
        c1 *= inv;
        int row = b * 2048 + qb + qg * 32 + t * 16 + rr;
#pragma unroll
        for (int dt = 0; dt < 4; dt++) {
          float o1 = oex[((qg * 2 + t) * 16 + rr) * 64 + dt * 16 + r16];
          int col = h * 64 + dt * 16 + r16;
          o[(size_t)row * 512 + col] = f2bf(oacc[t][dt][j] * c0 + o1 * c1);
        }
      }
  }
}

// ---------------- launcher ----------------
extern "C" void kernel_launch(void* const* d_in, const int* in_sizes, int n_in,
                              void* d_out, int out_size, void* d_ws, size_t ws_size,
                              hipStream_t stream) {
  const float* z = (const float*)d_in[0];
  const float* head_w = (const float*)d_in[1];
  const float* w_o = (const float*)d_in[2];
  const float* ln_w = (const float*)d_in[3];
  const float* ln_b = (const float*)d_in[4];
  const float* w1 = (const float*)d_in[5];
  const float* b1 = (const float*)d_in[6];
  const float* w2 = (const float*)d_in[7];
  const float* b2 = (const float*)d_in[8];
  float* out = (float*)d_out;

  size_t off = 0;
  auto alc = [&](size_t n) {
    void* p = (char*)d_ws + off;
    off += (n + 255) & ~(size_t)255;
    return p;
  };
  u16* x_hi = (u16*)alc((size_t)4096 * 512 * 2);
  u16* x_lo = (u16*)alc((size_t)4096 * 512 * 2);
  u16* wqh = (u16*)alc((size_t)1536 * 512 * 2);
  u16* wql = (u16*)alc((size_t)1536 * 512 * 2);
  u16* woT = (u16*)alc((size_t)512 * 512 * 2);
  u16* w1T = (u16*)alc((size_t)128 * 512 * 2);
  u16* w2T = (u16*)alc((size_t)512 * 128 * 2);
  u16* qkh = (u16*)alc((size_t)4096 * 1024 * 2);
  u16* qkl = (u16*)alc((size_t)4096 * 1024 * 2);
  u16* vT = (u16*)alc((size_t)512 * 4096 * 2);
  u16* ob = (u16*)alc((size_t)4096 * 512 * 2);
  float* z2 = (float*)alc((size_t)4096 * 512 * 4);
  u16* tb = (u16*)alc((size_t)4096 * 128 * 2);

  prep_all<<<4608, 256, 0, stream>>>(head_w, w_o, w1, w2, wqh, wql, woT, w1T, w2T);

  // LN1: z -> x hi/lo
  ln_kernel<<<1024, 256, 0, stream>>>(z, ln_w, ln_b, x_hi, x_lo);

  // QKV projection (r4 tiling); V written transposed to vT
  gemm_qkv<<<dim3(32, 24), 256, 0, stream>>>(x_hi, x_lo, wqh, wql, qkh, qkl, vT);

  // flash attention v11 (2 qg x 2 kv-half waves, t-sharing)
  attn_kernel<<<dim3(32, 16), 256, 0, stream>>>(qkh, qkl, vT, ob);

  // z2 = o @ w_o + z
  gemm_g<2, 2, 1><<<dim3(64, 8), 256, 0, stream>>>(ob, woT, z, nullptr, nullptr, z2, 512, 512);

  // LN2
  ln_kernel<<<1024, 256, 0, stream>>>(z2, ln_w, ln_b, x_hi, x_lo);

  // t = y @ w1 + b1
  gemm_g<1, 2, 2><<<dim3(128, 2), 256, 0, stream>>>(x_hi, w1T, nullptr, b1, tb, nullptr, 128, 512);

  // out = gelu(t @ w2 + b2) + z2
  gemm_g<2, 2, 3><<<dim3(64, 8), 256, 0, stream>>>(tb, w2T, z2, b2, nullptr, out, 512, 128);
}